// Round 6
// baseline (243.647 us; speedup 1.0000x reference)
//
#include <hip/hip_runtime.h>
#include <hip/hip_bf16.h>
#include <math.h>

#define EMBED 1024
#define HEADS 16
#define DH    64
#define BATCH 2
#define SEQ   2048

typedef __attribute__((ext_vector_type(8))) short bf16x8;
typedef __attribute__((ext_vector_type(4))) short bf16x4;
typedef __attribute__((ext_vector_type(4))) float f32x4;
typedef unsigned long long u64;

#define QSCALE 0.1803368801111244f   // 0.125 * log2(e): exp(s/8) == exp2(s*QSCALE)

static __device__ __forceinline__ unsigned short f2bf(float x) {
    unsigned u = __builtin_bit_cast(unsigned, x);
    return (unsigned short)((u + 0x7fffu + ((u >> 16) & 1u)) >> 16);
}
static __device__ __forceinline__ unsigned pk2bf(float a, float b) {
    union { __hip_bfloat162 h2; unsigned u; } c;
    c.h2 = __float22bfloat162_rn(make_float2(a, b));
    return c.u;
}
// async global->LDS DMA, 16 B per lane; LDS dest = wave-uniform base + lane*16
static __device__ __forceinline__ void gl_lds16(const void* g, void* l) {
    __builtin_amdgcn_global_load_lds(
        (const __attribute__((address_space(1))) void*)g,
        (__attribute__((address_space(3))) void*)l, 16, 0, 0);
}
// convert 16 consecutive fp32 (two float4 pairs) to one bf16x8 fragment
static __device__ __forceinline__ bf16x8 cvt8(const float* p) {
    float4 a = ((const float4*)p)[0];
    float4 b = ((const float4*)p)[1];
    union { unsigned u[4]; bf16x8 v; } c;
    c.u[0] = pk2bf(a.x, a.y); c.u[1] = pk2bf(a.z, a.w);
    c.u[2] = pk2bf(b.x, b.y); c.u[3] = pk2bf(b.z, b.w);
    return c.v;
}

// ---------------------------------------------------------------------------
// Kernel 1 (R6 mega-proj): grid = (1024, 4), block = 256.
//   which 0: Q projection, C = X·W^T, out layout [B,H,S,DH] (unchanged).
//   which 1: K projection, C = X·W^T, out in FRAGMENT-MAJOR layout
//            Kp[bh][s>>4][d>>3][s&15][d&7] so attn's QK fragment loads are
//            single fully-coalesced 1KB wave reads straight from L2.
//   which 2: V projection TRANSPOSED, C = W·X^T -> vt[bh][d][s] (R5).
//   which 3: blk<512 maskpack | blk>=512 Wo fp32->bf16 (R5).
// ---------------------------------------------------------------------------
__global__ __launch_bounds__(256) void proj_mfma(
    const float* __restrict__ q, const float* __restrict__ k, const float* __restrict__ v,
    const float* __restrict__ Wq, const float* __restrict__ bq,
    const float* __restrict__ Wk, const float* __restrict__ bk,
    const float* __restrict__ Wv, const float* __restrict__ bv,
    unsigned short* __restrict__ qh, unsigned short* __restrict__ Kp,
    unsigned short* __restrict__ vt,
    const int* __restrict__ mask, u64* __restrict__ bits,
    const float* __restrict__ Wo, unsigned short* __restrict__ Wob)
{
    const int blk   = blockIdx.x;
    const int which = blockIdx.y;
    const int t     = threadIdx.x;

    if (which == 3) {                     // ---- prep jobs (no LDS, no barrier) ----
        if (blk < 512) {                  // mask -> bitmask
            const int idx = blk * 256 + t;
            const int4* src = (const int4*)(mask + (size_t)idx * 64);
            u64 wb = 0;
#pragma unroll
            for (int u = 0; u < 16; ++u) {
                int4 m = src[u];
                u64 nib = (m.x != 0 ? 1ull : 0) | (m.y != 0 ? 2ull : 0) |
                          (m.z != 0 ? 4ull : 0) | (m.w != 0 ? 8ull : 0);
                wb |= nib << (u * 4);
            }
            bits[idx] = wb;
        } else {                          // Wo fp32 -> bf16
            const int i = ((blk - 512) * 256 + t) * 8;
            float4 a = ((const float4*)(Wo + i))[0];
            float4 b = ((const float4*)(Wo + i))[1];
            unsigned o32[4] = {pk2bf(a.x, a.y), pk2bf(a.z, a.w),
                               pk2bf(b.x, b.y), pk2bf(b.z, b.w)};
            *(uint4*)(Wob + i) = *(uint4*)o32;
        }
        return;
    }

    const float* x; const float* W; const float* bias;
    if (which == 0)      { x = q; W = Wq; bias = bq; }
    else if (which == 1) { x = k; W = Wk; bias = bk; }
    else                 { x = v; W = Wv; bias = bv; }

    __shared__ unsigned short Ws[64 * 72];

    const int w    = t >> 6;
    const int lane = t & 63;
    const int l15  = lane & 15;
    const int quad = lane >> 4;

    // ---- stage W into LDS (cooperative, one pass; verified R2 layout) ----
    const int sr = t >> 2, sp = t & 3;
    {
        const float* wsrc = W + (size_t)sr * 64 + sp * 16;
        unsigned o32[8];
#pragma unroll
        for (int u4 = 0; u4 < 4; ++u4) {
            float4 a = ((const float4*)wsrc)[u4];
            o32[u4 * 2 + 0] = pk2bf(a.x, a.y);
            o32[u4 * 2 + 1] = pk2bf(a.z, a.w);
        }
        *(uint4*)&Ws[sr * 72 + sp * 16]     = *(uint4*)&o32[0];
        *(uint4*)&Ws[sr * 72 + sp * 16 + 8] = *(uint4*)&o32[4];
    }

    if (which == 2) {                     // ---- V: C = W·X^T -> vt[bh][d][s] ----
        const int bh = blk >> 5;          // (b,h) 0..31
        const int st = blk & 31;          // s-tile
        const int b  = bh >> 4, h = bh & 15;
        const int s  = st * 64 + w * 16 + l15;

        const float* xrow = x + ((size_t)(b * SEQ + s)) * EMBED + h * DH;
        const bf16x8 bx0 = cvt8(xrow + quad * 8);
        const bf16x8 bx1 = cvt8(xrow + 32 + quad * 8);

        __syncthreads();

#pragma unroll
        for (int nt = 0; nt < 4; ++nt) {
            bf16x8 aw0 = *(const bf16x8*)&Ws[(nt * 16 + l15) * 72 + quad * 8];
            bf16x8 aw1 = *(const bf16x8*)&Ws[(nt * 16 + l15) * 72 + 32 + quad * 8];
            f32x4 a = {0, 0, 0, 0};
            a = __builtin_amdgcn_mfma_f32_16x16x32_bf16(aw0, bx0, a, 0, 0, 0);
            a = __builtin_amdgcn_mfma_f32_16x16x32_bf16(aw1, bx1, a, 0, 0, 0);
#pragma unroll
            for (int r = 0; r < 4; ++r) {
                const int d = nt * 16 + quad * 4 + r;
                vt[((size_t)bh * DH + d) * SEQ + s] = f2bf(a[r] + bias[d]);
            }
        }
        return;
    }

    // ---- Q/K: C = X·W^T (R4 hybrid path) ----
    const float oscale = (which == 0) ? QSCALE : 1.0f;

    const float* xrow = x + ((size_t)blk * 64 + w * 16 + l15) * 64;
    const bf16x8 af0 = cvt8(xrow + quad * 8);
    const bf16x8 af1 = cvt8(xrow + 32 + quad * 8);

    __syncthreads();

    f32x4 acc[4];
#pragma unroll
    for (int nt = 0; nt < 4; ++nt) {
        bf16x8 bf0 = *(const bf16x8*)&Ws[(nt * 16 + l15) * 72 + quad * 8];
        bf16x8 bf1 = *(const bf16x8*)&Ws[(nt * 16 + l15) * 72 + 32 + quad * 8];
        f32x4 a = {0, 0, 0, 0};
        a = __builtin_amdgcn_mfma_f32_16x16x32_bf16(af0, bf0, a, 0, 0, 0);
        a = __builtin_amdgcn_mfma_f32_16x16x32_bf16(af1, bf1, a, 0, 0, 0);
        acc[nt] = a;
    }

    const int bsidx = blk * 4 + w;
    const int b = bsidx >> 11, s = bsidx & 2047;

    if (which == 0) {                     // Q out: [B,H,S,DH]
#pragma unroll
        for (int nt = 0; nt < 4; ++nt) {
            const int d = nt * 16 + l15;
            const float bb = bias[d];
#pragma unroll
            for (int r = 0; r < 4; ++r) {
                const int h = quad * 4 + r;
                qh[(((size_t)b * HEADS + h) * SEQ + s) * DH + d] =
                    f2bf((acc[nt][r] + bb) * oscale);
            }
        }
    } else {                              // K out: fragment-major Kp
        const int sg = s >> 4, sr16 = s & 15;
#pragma unroll
        for (int nt = 0; nt < 4; ++nt) {
            const int d  = nt * 16 + l15;
            const int dc = d >> 3, d7 = d & 7;
            const float bb = bias[d];
#pragma unroll
            for (int r = 0; r < 4; ++r) {
                const int h = quad * 4 + r;
                // Kp[((bh*128 + sg)*8 + dc)*128 + sr16*8 + d7]
                Kp[(((size_t)(b * HEADS + h) * 128 + sg) * 8 + dc) * 128
                   + sr16 * 8 + d7] = f2bf(acc[nt][r] + bb);
            }
        }
    }
}

// ---------------------------------------------------------------------------
// Kernel 2 (R6): MFMA flash attention — K read DIRECTLY from L2 (fragment-
// major Kp layout, one coalesced 1KB wave-load per fragment; no K-LDS, no
// K-DMA, no 8-way ds_read conflict). V stays LDS-staged (2 x 8KB double
// buffer, DMA spread over all 4 waves). s_setprio(1) around per-tile compute.
// grid = flat 1024; bh = bid & 31 for XCD-local K/V reuse.
// ---------------------------------------------------------------------------
__global__ __launch_bounds__(256, 4) void attn_kernel(
    const unsigned short* __restrict__ qh, const unsigned short* __restrict__ Kp,
    const unsigned short* __restrict__ vt, const u64* __restrict__ mbits,
    unsigned short* __restrict__ ctx)
{
    const int bid = blockIdx.x;
    const int bh  = bid & 31;
    const int q0  = (bid >> 5) * 64;
    const int b   = bh >> 4;

    __shared__ unsigned char smem[16384];   // V only: buf(8K) x2

    const int t    = threadIdx.x;
    const int w    = t >> 6;              // wave id: q-subtile (16 rows)
    const int lane = t & 63;
    const int l15  = lane & 15;
    const int quad = lane >> 4;

    const int srow   = lane >> 3;
    const int schunk = (lane & 7) ^ srow;

    const unsigned short* qb = qh + ((size_t)bh * SEQ + q0 + w * 16 + l15) * DH + quad * 8;
    const bf16x8 qf0 = *(const bf16x8*)qb;
    const bf16x8 qf1 = *(const bf16x8*)(qb + 32);

    f32x4 O[4];
#pragma unroll
    for (int dt = 0; dt < 4; ++dt) O[dt] = f32x4{0, 0, 0, 0};
    f32x4 Osum = {0, 0, 0, 0};
    const bf16x4 ones = {(short)0x3F80, (short)0x3F80, (short)0x3F80, (short)0x3F80};

    // K fragment-major base: Kp[bh][G][c][r][8]; one G-row = 1024 ushorts.
    const unsigned short* kp = Kp + (size_t)bh * 128 * 1024 + lane * 8;

    const unsigned short* vbase = vt + (size_t)bh * DH * SEQ
                                  + (size_t)srow * SEQ + schunk * 8;
    const u64* mrow = mbits + ((size_t)b * SEQ + q0 + w * 16 + l15) * (SEQ / 64);

    // issue V-DMA for tile 0 into buf 0 (all 4 waves, 2 issues each)
    {
        unsigned char* Vd = smem;
#pragma unroll
        for (int j = 0; j < 2; ++j) {
            const int i = w * 2 + j;
            gl_lds16(vbase + (size_t)i * 8 * SEQ, Vd + i * 1024);
        }
    }
    u64 pm = mrow[0];
    __syncthreads();                      // drains DMA(0)

    for (int kt = 0; kt < 32; ++kt) {
        // ---- issue V-DMA for tile kt+1 into the other buffer ----
        if (kt < 31) {
            unsigned char* Vd = smem + ((kt + 1) & 1) * 8192;
            const unsigned short* g0 = vbase + (kt + 1) * 64;
#pragma unroll
            for (int j = 0; j < 2; ++j) {
                const int i = w * 2 + j;
                gl_lds16(g0 + (size_t)i * 8 * SEQ, Vd + i * 1024);
            }
        }
        const u64 mb = pm;
        if (kt < 31) pm = mrow[kt + 1];

        const unsigned short* VtH = (const unsigned short*)(smem + (kt & 1) * 8192);
        const unsigned short* kpt = kp + (size_t)kt * 4 * 1024;

        __builtin_amdgcn_s_setprio(1);

        // ---- S^T tile + masked exp2; K frags straight from L2 ----
        const u64 mq = mb >> (quad * 4);
        bf16x4 p[4];
#pragma unroll
        for (int st = 0; st < 4; ++st) {
            bf16x8 kf0 = *(const bf16x8*)&kpt[st * 1024];
            bf16x8 kf1 = *(const bf16x8*)&kpt[st * 1024 + 512];
            f32x4 sa = {0, 0, 0, 0};
            sa = __builtin_amdgcn_mfma_f32_16x16x32_bf16(kf0, qf0, sa, 0, 0, 0);
            sa = __builtin_amdgcn_mfma_f32_16x16x32_bf16(kf1, qf1, sa, 0, 0, 0);
            const unsigned nib = (unsigned)(mq >> (st * 16)) & 0xFu;
            float p0 = (nib & 1u) ? exp2f(sa[0]) : 0.f;
            float p1 = (nib & 2u) ? exp2f(sa[1]) : 0.f;
            float p2 = (nib & 4u) ? exp2f(sa[2]) : 0.f;
            float p3 = (nib & 8u) ? exp2f(sa[3]) : 0.f;
            union { unsigned u2[2]; bf16x4 v; } pu;
            pu.u2[0] = pk2bf(p0, p1);
            pu.u2[1] = pk2bf(p2, p3);
            p[st] = pu.v;
            Osum = __builtin_amdgcn_mfma_f32_16x16x16bf16_1k(p[st], ones, Osum, 0, 0, 0);
        }

        // ---- PV: O[dt] += P * V (B-frags from swizzled Vt; unchanged) ----
#pragma unroll
        for (int dt = 0; dt < 4; ++dt) {
            const int d = dt * 16 + l15;
            const int dx = l15 & 7;
#pragma unroll
            for (int st = 0; st < 4; ++st) {
                const int ch = (st * 2 + (quad >> 1)) ^ dx;
                bf16x4 vb = *(const bf16x4*)&VtH[d * 64 + ch * 8 + (quad & 1) * 4];
                O[dt] = __builtin_amdgcn_mfma_f32_16x16x16bf16_1k(p[st], vb, O[dt], 0, 0, 0);
            }
        }
        __builtin_amdgcn_s_setprio(0);
        __syncthreads();   // readers done with buf(kt); drains DMA(kt+1) post-compute
    }

    // ---- epilogue: direct store, wave-local denominator ----
    float inv[4];
#pragma unroll
    for (int r = 0; r < 4; ++r) inv[r] = 1.0f / Osum[r];
#pragma unroll
    for (int r = 0; r < 4; ++r) {
        const int row = q0 + w * 16 + quad * 4 + r;
        unsigned short* dst = ctx + ((size_t)bh * SEQ + row) * DH + l15;
#pragma unroll
        for (int dt = 0; dt < 4; ++dt)
            dst[dt * 16] = f2bf(O[dt][r] * inv[r]);
    }
}

// ---------------------------------------------------------------------------
// Kernel 3: output projection via MFMA, DMA-staged + double-buffered.
// (frozen)
// ---------------------------------------------------------------------------
__global__ __launch_bounds__(256, 4) void outproj_mfma(
    const unsigned short* __restrict__ ctx, const unsigned short* __restrict__ Wob,
    const float* __restrict__ bo, float* __restrict__ out)
{
    const int n0 = blockIdx.x * 64;
    const int m0 = blockIdx.y * 64;
    const int b  = m0 / SEQ;
    const int s0 = m0 % SEQ;

    __shared__ unsigned char smem[32768];   // buf(16K) x2: [A 8K | W 8K]

    const int t    = threadIdx.x;
    const int w    = t >> 6;
    const int lane = t & 63;
    const int l15  = lane & 15;
    const int quad = lane >> 4;
    const int srow   = lane >> 3;
    const int schunk = (lane & 7) ^ srow;

    const unsigned short* abase = ctx + ((size_t)b * HEADS * SEQ + s0 + srow) * DH + schunk * 8;
    const unsigned short* wbase = Wob + (size_t)(n0 + srow) * EMBED + schunk * 8;

    f32x4 acc[4] = {f32x4{0,0,0,0}, f32x4{0,0,0,0}, f32x4{0,0,0,0}, f32x4{0,0,0,0}};

    {
        unsigned char* Ab = smem;
        unsigned char* Wb = smem + 8192;
#pragma unroll
        for (int j = 0; j < 4; ++j) {
            const int idx = w * 4 + j;
            if (idx < 8)
                gl_lds16(abase + (size_t)idx * 8 * DH, Ab + idx * 1024);
            else
                gl_lds16(wbase + (size_t)(idx - 8) * 8 * EMBED, Wb + (idx - 8) * 1024);
        }
    }
    __syncthreads();

    for (int kt = 0; kt < 16; ++kt) {
        if (kt < 15) {
            const int ktn = kt + 1;
            unsigned char* Ab = smem + (ktn & 1) * 16384;
            unsigned char* Wb = Ab + 8192;
#pragma unroll
            for (int j = 0; j < 4; ++j) {
                const int idx = w * 4 + j;
                if (idx < 8)
                    gl_lds16(abase + (size_t)ktn * SEQ * DH + (size_t)idx * 8 * DH,
                             Ab + idx * 1024);
                else
                    gl_lds16(wbase + (size_t)(idx - 8) * 8 * EMBED + ktn * 64,
                             Wb + (idx - 8) * 1024);
            }
        }

        const unsigned short* At = (const unsigned short*)(smem + (kt & 1) * 16384);
        const unsigned short* Wt = At + 4096;
        const int rx = l15 & 7;
        const int c0 = ((quad ^ rx)) * 8;

        bf16x8 bf0 = *(const bf16x8*)&Wt[(w * 16 + l15) * 64 + c0];
        bf16x8 bf1 = *(const bf16x8*)&Wt[(w * 16 + l15) * 64 + (c0 ^ 32)];
#pragma unroll
        for (int mt = 0; mt < 4; ++mt) {
            bf16x8 af0 = *(const bf16x8*)&At[(mt * 16 + l15) * 64 + c0];
            bf16x8 af1 = *(const bf16x8*)&At[(mt * 16 + l15) * 64 + (c0 ^ 32)];
            acc[mt] = __builtin_amdgcn_mfma_f32_16x16x32_bf16(af0, bf0, acc[mt], 0, 0, 0);
            acc[mt] = __builtin_amdgcn_mfma_f32_16x16x32_bf16(af1, bf1, acc[mt], 0, 0, 0);
        }
        __syncthreads();
    }

    const float bv = bo[n0 + w * 16 + l15];
#pragma unroll
    for (int mt = 0; mt < 4; ++mt) {
#pragma unroll
        for (int r = 0; r < 4; ++r) {
            out[(size_t)(m0 + mt * 16 + quad * 4 + r) * EMBED + n0 + w * 16 + l15] =
                acc[mt][r] + bv;
        }
    }
}

// ---------------------------------------------------------------------------
extern "C" void kernel_launch(void* const* d_in, const int* in_sizes, int n_in,
                              void* d_out, int out_size, void* d_ws, size_t ws_size,
                              hipStream_t stream) {
    const float* k    = (const float*)d_in[0];
    const float* q    = (const float*)d_in[1];
    const float* v    = (const float*)d_in[2];
    const int*   mask = (const int*)  d_in[3];
    const float* Wk   = (const float*)d_in[4];
    const float* bk   = (const float*)d_in[5];
    const float* Wq   = (const float*)d_in[6];
    const float* bq   = (const float*)d_in[7];
    const float* Wv   = (const float*)d_in[8];
    const float* bv   = (const float*)d_in[9];
    const float* Wo   = (const float*)d_in[10];
    const float* bo   = (const float*)d_in[11];
    float* out = (float*)d_out;

    const size_t TEN = (size_t)BATCH * HEADS * SEQ * DH;   // 4,194,304 elems
    unsigned short* qh_bf = (unsigned short*)d_ws;         // 8 MB
    unsigned short* kp_bf = qh_bf + TEN;                   // 8 MB (fragment-major K)
    unsigned short* vt_bf = kp_bf + TEN;                   // 8 MB
    unsigned short* ctxb  = vt_bf + TEN;                   // 8 MB
    unsigned short* Wob   = ctxb + TEN;                    // 2 MB
    u64*            mbits = (u64*)(Wob + EMBED * EMBED);   // 1 MB  (35 MB total)

    proj_mfma<<<dim3(1024, 4), 256, 0, stream>>>(
        q, k, v, Wq, bq, Wk, bk, Wv, bv,
        qh_bf, kp_bf, vt_bf, mask, mbits, Wo, Wob);
    attn_kernel<<<dim3((SEQ / 64) * BATCH * HEADS), 256, 0, stream>>>(
        qh_bf, kp_bf, vt_bf, mbits, ctxb);
    outproj_mfma<<<dim3(EMBED / 64, BATCH * SEQ / 64), 256, 0, stream>>>(
        ctxb, Wob, bo, out);
}